// Round 12
// baseline (29.809 us; speedup 1.0000x reference)
//
#include <hip/hip_runtime.h>
#include <hip/hip_bf16.h>

// Problem constants (match reference)
#define BB 16384
#define DD 512
#define NCLS 90
#define KC 32
#define BUCKET 512   // max samples per class (mean 182, +24 sigma headroom)
#define PRB 180      // center-norm blocks in k_prep (2880 rows / 16 waves)
#define NSL 12       // chunk-slots per class (chunk = 16 samples)

typedef __attribute__((ext_vector_type(8))) short short8;   // 8 bf16 (4 VGPRs)
typedef __attribute__((ext_vector_type(4))) float fx4;      // MFMA accumulator

static __device__ __forceinline__ short f2bf(float f) {
    unsigned u = __float_as_uint(f);
    unsigned r = (u + 0x7fffu + ((u >> 16) & 1u)) >> 16;    // RNE
    return (short)r;
}
// pack 8 f32 -> 8 bf16 (RNE, v_cvt_pk_bf16_f32)
static __device__ __forceinline__ short8 pack8(float4 a, float4 b) {
    union { __hip_bfloat162 h[4]; short8 s; } u;
    u.h[0] = __float22bfloat162_rn(make_float2(a.x, a.y));
    u.h[1] = __float22bfloat162_rn(make_float2(a.z, a.w));
    u.h[2] = __float22bfloat162_rn(make_float2(b.x, b.y));
    u.h[3] = __float22bfloat162_rn(make_float2(b.z, b.w));
    return u.s;
}
static __device__ __forceinline__ void gload_lds16(const void* g, void* l) {
    __builtin_amdgcn_global_load_lds(
        (const __attribute__((address_space(1))) void*)g,
        (__attribute__((address_space(3))) void*)l, 16, 0, 0);
}

// ------- kernel 1: prep (R9-verbatim, proven) --------------------------------
__global__ __launch_bounds__(1024)
void k_prep(const float* __restrict__ centers, const int* __restrict__ labels,
            short* __restrict__ cni, int* __restrict__ idx, int* __restrict__ cnt) {
    __shared__ int lab[BB];       // 64 KiB label cache for binning blocks
    __shared__ int wcnt[16];

    int t = threadIdx.x, w = t >> 6, lane = t & 63;

    if ((int)blockIdx.x < PRB) {
        int row = blockIdx.x * 16 + w;                  // 0..2879
        const float4* p = (const float4*)(centers + (size_t)row * DD);
        float4 a = p[lane * 2];
        float4 b = p[lane * 2 + 1];
        float s = a.x * a.x + a.y * a.y + a.z * a.z + a.w * a.w
                + b.x * b.x + b.y * b.y + b.z * b.z + b.w * b.w;
#pragma unroll
        for (int m = 1; m < 64; m <<= 1) s += __shfl_xor(s, m, 64);
        float sc = rsqrtf(s + 1e-12f);
        short8 v;
        v[0] = f2bf(a.x * sc); v[1] = f2bf(a.y * sc);
        v[2] = f2bf(a.z * sc); v[3] = f2bf(a.w * sc);
        v[4] = f2bf(b.x * sc); v[5] = f2bf(b.y * sc);
        v[6] = f2bf(b.z * sc); v[7] = f2bf(b.w * sc);
        *(short8*)(cni + (size_t)row * DD + lane * 8) = v;
    } else {
        int c = blockIdx.x - PRB;
        for (int j = t; j < BB / 4; j += 1024)
            ((int4*)lab)[j] = ((const int4*)labels)[j];
        __syncthreads();

        int seg4 = w * (BB / 4 / 16);
        int cw = 0;
#pragma unroll
        for (int jj = 0; jj < 4; jj++) {
            int4 v = ((int4*)lab)[seg4 + jj * 64 + lane];
            cw += (v.x == c) + (v.y == c) + (v.z == c) + (v.w == c);
        }
#pragma unroll
        for (int m = 1; m < 64; m <<= 1) cw += __shfl_xor(cw, m, 64);
        if (lane == 0) wcnt[w] = cw;
        __syncthreads();
        int pos = c * BUCKET;
        for (int ww = 0; ww < w; ww++) pos += wcnt[ww];
#pragma unroll
        for (int jj = 0; jj < 4; jj++) {
            int4 v = ((int4*)lab)[seg4 + jj * 64 + lane];
            int gbase = (seg4 + jj * 64 + lane) * 4;
            { bool m = (v.x == c); unsigned long long k = __ballot(m);
              if (m) idx[pos + __popcll(k & ((1ull << lane) - 1ull))] = gbase;     pos += __popcll(k); }
            { bool m = (v.y == c); unsigned long long k = __ballot(m);
              if (m) idx[pos + __popcll(k & ((1ull << lane) - 1ull))] = gbase + 1; pos += __popcll(k); }
            { bool m = (v.z == c); unsigned long long k = __ballot(m);
              if (m) idx[pos + __popcll(k & ((1ull << lane) - 1ull))] = gbase + 2; pos += __popcll(k); }
            { bool m = (v.w == c); unsigned long long k = __ballot(m);
              if (m) idx[pos + __popcll(k & ((1ull << lane) - 1ull))] = gbase + 3; pos += __popcll(k); }
        }
        if (t == 0) {
            int s = 0;
#pragma unroll
            for (int i = 0; i < 16; i++) s += wcnt[i];
            cnt[c] = s;
        }
    }
}

// ------- kernel 2: main — async-gather chunk-16, k-split wave pairs ----------
// Block (c = b/12, slot p = b%12), 256 thr. Per chunk of 16 samples:
//   x rows gload_lds'd as raw f32 (source-swizzled, dest linear per row),
//   waves {0,1} compute k 0..255, waves {2,3} k 256..511 (partial dots),
//   wave w covers centers (w&1)*16..+15; norms accumulated from A-fragments
//   inside the MFMA loop; partial dots + half-norms combined in S_lds/xn2.
__global__ __launch_bounds__(256, 2)
void k_main(const float* __restrict__ x,
            const short* __restrict__ cni,
            const int* __restrict__ cnt,
            const int* __restrict__ idx,
            float* __restrict__ partials) {
    __shared__ __align__(16) short c_lds[KC * DD];   // 32 KiB bf16, XOR-swizzled
    __shared__ __align__(16) float xf[16 * DD];      // 32 KiB f32, 16B-chunk swz
    __shared__ float S[2][16][34];                   // k-half partial dots
    __shared__ float xn2[2][16];                     // k-half partial sq-norms
    __shared__ float red[256];

    int b = blockIdx.x;
    int c = b / NSL, p = b % NSL;
    int n = cnt[c];
    int nch = (n + 15) >> 4;
    int t = threadIdx.x, w = t >> 6, lane = t & 63;
    float loss = 0.f;

    if (p < nch) {
        // ---- stage class centers (bf16 image) via async gload (R9-proven) ----
        const short* cbase = cni + (size_t)c * KC * DD;
#pragma unroll
        for (int it = 0; it < 8; it++) {
            int q = t + 256 * it;                 // 16B chunk 0..2047, linear LDS
            int drow = q >> 6, cc = q & 63;
            gload_lds16(cbase + drow * DD + (cc ^ (drow & 7)) * 8, &c_lds[q * 8]);
        }

        int r = lane & 15, g4 = lane >> 4;
        int kh = w >> 1, chf = w & 1;             // k-half, center-half
        int nrow = (chf << 4) + r;                // center row in c_lds
        int srow = t >> 4, l16 = t & 15;          // softmax: 16 thr per sample

        for (int ch = p; ch < nch; ch += NSL) {
            int off = ch << 4;
            int rem = n - off;                    // > 0

            // ---- async-stage 16 gathered f32 rows; wave w stages rows w*4..+3
            int gi = 0;
            if (lane < 4) {
                int i = off + (w << 2) + lane; if (i > n - 1) i = n - 1;
                gi = idx[c * BUCKET + i];
            }
#pragma unroll
            for (int j = 0; j < 4; j++) {
                int row = (w << 2) + j;
                int g = __shfl(gi, j, 64);
                const char* src = (const char*)(x + (size_t)g * DD);
                int sl = (lane ^ (row & 7)) << 4;         // pre-swizzled source
                gload_lds16(src + sl,        &xf[row * DD]);
                gload_lds16(src + 1024 + sl, &xf[row * DD + 256]);
            }
            __syncthreads();                       // drains all gload_lds

            // ---- MFMA: 8 k-steps of this wave's k-half; norm from fragments --
            fx4 acc = {0.f, 0.f, 0.f, 0.f};
            float nrm = 0.f;
#pragma unroll
            for (int ks = 0; ks < 8; ks++) {
                int cq = (kh * 8 + ks) * 4 + g4;          // 32B fragment 0..63
                int p0 = (2 * cq) ^ (r & 7);              // physical 16B chunks
                int p1 = (2 * cq + 1) ^ (r & 7);
                float4 a0 = *(const float4*)&xf[r * DD + p0 * 4];
                float4 a1 = *(const float4*)&xf[r * DD + p1 * 4];
                nrm += a0.x * a0.x + a0.y * a0.y + a0.z * a0.z + a0.w * a0.w
                     + a1.x * a1.x + a1.y * a1.y + a1.z * a1.z + a1.w * a1.w;
                short8 av = pack8(a0, a1);
                short8 bv = *(const short8*)&c_lds[nrow * DD + ((cq ^ (nrow & 7)) << 3)];
                acc = __builtin_amdgcn_mfma_f32_16x16x32_bf16(av, bv, acc, 0, 0, 0);
            }
            nrm += __shfl_xor(nrm, 16, 64);
            nrm += __shfl_xor(nrm, 32, 64);        // every lane: half-norm of row r
            if (chf == 0 && g4 == 0) xn2[kh][r] = nrm;
#pragma unroll
            for (int j = 0; j < 4; j++)            // D: sample=(g4*4+j), center=r
                S[kh][(g4 << 2) + j][(chf << 4) + r] = acc[j];
            __syncthreads();

            // ---- combine k-halves + softmax; 16 threads per sample ----
            {
                float xv = rsqrtf(xn2[0][srow] + xn2[1][srow] + 1e-12f);
                int c0 = l16 * 2;
                float sa = (S[0][srow][c0]     + S[1][srow][c0])     * xv;
                float sb = (S[0][srow][c0 + 1] + S[1][srow][c0 + 1]) * xv;
                float mx = fmaxf(sa, sb);
#pragma unroll
                for (int m = 1; m < 16; m <<= 1) mx = fmaxf(mx, __shfl_xor(mx, m, 64));
                float ea = expf(sa - mx), eb = expf(sb - mx);
                float Z = ea + eb;
                float num = ea * (1.f - sa) + eb * (1.f - sb);
#pragma unroll
                for (int m = 1; m < 16; m <<= 1) {
                    Z   += __shfl_xor(Z, m, 64);
                    num += __shfl_xor(num, m, 64);
                }
                if (l16 == 0 && srow < rem) loss += num / Z;
            }
            // next iteration's stage starts only after this thread's softmax;
            // the pre-MFMA barrier orders it against all other threads.
        }
    }

    // ---- per-block fixed-order partial reduction (all blocks write) ----
    red[t] = loss;
    __syncthreads();
    for (int h = 128; h > 0; h >>= 1) {
        if (t < h) red[t] += red[t + h];
        __syncthreads();
    }
    if (t == 0) partials[b] = red[0];
}

// ------- kernel 3: deterministic final mean over 1080 block partials ---------
__global__ void k_final(const float* __restrict__ partials, float* __restrict__ out) {
    __shared__ float red[256];
    int t = threadIdx.x;
    float s = 0.f;
    for (int i = t; i < NCLS * NSL; i += 256) s += partials[i];
    red[t] = s;
    __syncthreads();
    for (int h = 128; h > 0; h >>= 1) {
        if (t < h) red[t] += red[t + h];
        __syncthreads();
    }
    if (t == 0) out[0] = red[0] * (1.0f / (float)BB);
}

extern "C" void kernel_launch(void* const* d_in, const int* in_sizes, int n_in,
                              void* d_out, int out_size, void* d_ws, size_t ws_size,
                              hipStream_t stream) {
    const float* x       = (const float*)d_in[0];
    const int*   labels  = (const int*)d_in[1];
    const float* centers = (const float*)d_in[2];
    float* out = (float*)d_out;

    char* ws = (char*)d_ws;
    short* cni      = (short*)(ws + 0);             // 2880*512 bf16 = 2,949,120 B
    int*   idx      = (int*)(ws + 3145728);         // 90*512 ints   =   184,320 B
    int*   cnt      = (int*)(ws + 3407872);         // 90 ints
    float* partials = (float*)(ws + 3473408);       // 1080 floats (all written)

    k_prep<<<PRB + NCLS, 1024, 0, stream>>>(centers, labels, cni, idx, cnt);
    k_main<<<NCLS * NSL, 256, 0, stream>>>(x, cni, cnt, idx, partials);
    k_final<<<1, 256, 0, stream>>>(partials, out);
}

// Round 13
// 27.857 us; speedup vs baseline: 1.0701x; 1.0701x over previous
//
#include <hip/hip_runtime.h>
#include <hip/hip_bf16.h>

// Problem constants (match reference)
#define BB 16384
#define DD 512
#define NCLS 90
#define KC 32
#define BUCKET 512   // max samples per class (mean 182, +24 sigma headroom)
#define PRB 180      // center-norm blocks in k_prep (2880 rows / 16 waves)

typedef __attribute__((ext_vector_type(8))) short short8;   // 8 bf16 (4 VGPRs)
typedef __attribute__((ext_vector_type(4))) float fx4;      // MFMA accumulator

static __device__ __forceinline__ short f2bf(float f) {
    unsigned u = __float_as_uint(f);
    unsigned r = (u + 0x7fffu + ((u >> 16) & 1u)) >> 16;    // RNE
    return (short)r;
}
// pack 8 f32 -> 8 bf16 (RNE, v_cvt_pk_bf16_f32)
static __device__ __forceinline__ short8 pack8(float4 a, float4 b) {
    union { __hip_bfloat162 h[4]; short8 s; } u;
    u.h[0] = __float22bfloat162_rn(make_float2(a.x, a.y));
    u.h[1] = __float22bfloat162_rn(make_float2(a.z, a.w));
    u.h[2] = __float22bfloat162_rn(make_float2(b.x, b.y));
    u.h[3] = __float22bfloat162_rn(make_float2(b.z, b.w));
    return u.s;
}
static __device__ __forceinline__ void gload_lds16(const void* g, void* l) {
    __builtin_amdgcn_global_load_lds(
        (const __attribute__((address_space(1))) void*)g,
        (__attribute__((address_space(3))) void*)l, 16, 0, 0);
}

// ------- kernel 1: prep (R9-verbatim, proven) --------------------------------
__global__ __launch_bounds__(1024)
void k_prep(const float* __restrict__ centers, const int* __restrict__ labels,
            short* __restrict__ cni, int* __restrict__ idx, int* __restrict__ cnt) {
    __shared__ int lab[BB];       // 64 KiB label cache for binning blocks
    __shared__ int wcnt[16];

    int t = threadIdx.x, w = t >> 6, lane = t & 63;

    if ((int)blockIdx.x < PRB) {
        int row = blockIdx.x * 16 + w;                  // 0..2879
        const float4* p = (const float4*)(centers + (size_t)row * DD);
        float4 a = p[lane * 2];
        float4 b = p[lane * 2 + 1];
        float s = a.x * a.x + a.y * a.y + a.z * a.z + a.w * a.w
                + b.x * b.x + b.y * b.y + b.z * b.z + b.w * b.w;
#pragma unroll
        for (int m = 1; m < 64; m <<= 1) s += __shfl_xor(s, m, 64);
        float sc = rsqrtf(s + 1e-12f);
        short8 v;
        v[0] = f2bf(a.x * sc); v[1] = f2bf(a.y * sc);
        v[2] = f2bf(a.z * sc); v[3] = f2bf(a.w * sc);
        v[4] = f2bf(b.x * sc); v[5] = f2bf(b.y * sc);
        v[6] = f2bf(b.z * sc); v[7] = f2bf(b.w * sc);
        *(short8*)(cni + (size_t)row * DD + lane * 8) = v;
    } else {
        int c = blockIdx.x - PRB;
        for (int j = t; j < BB / 4; j += 1024)
            ((int4*)lab)[j] = ((const int4*)labels)[j];
        __syncthreads();

        int seg4 = w * (BB / 4 / 16);
        int cw = 0;
#pragma unroll
        for (int jj = 0; jj < 4; jj++) {
            int4 v = ((int4*)lab)[seg4 + jj * 64 + lane];
            cw += (v.x == c) + (v.y == c) + (v.z == c) + (v.w == c);
        }
#pragma unroll
        for (int m = 1; m < 64; m <<= 1) cw += __shfl_xor(cw, m, 64);
        if (lane == 0) wcnt[w] = cw;
        __syncthreads();
        int pos = c * BUCKET;
        for (int ww = 0; ww < w; ww++) pos += wcnt[ww];
#pragma unroll
        for (int jj = 0; jj < 4; jj++) {
            int4 v = ((int4*)lab)[seg4 + jj * 64 + lane];
            int gbase = (seg4 + jj * 64 + lane) * 4;
            { bool m = (v.x == c); unsigned long long k = __ballot(m);
              if (m) idx[pos + __popcll(k & ((1ull << lane) - 1ull))] = gbase;     pos += __popcll(k); }
            { bool m = (v.y == c); unsigned long long k = __ballot(m);
              if (m) idx[pos + __popcll(k & ((1ull << lane) - 1ull))] = gbase + 1; pos += __popcll(k); }
            { bool m = (v.z == c); unsigned long long k = __ballot(m);
              if (m) idx[pos + __popcll(k & ((1ull << lane) - 1ull))] = gbase + 2; pos += __popcll(k); }
            { bool m = (v.w == c); unsigned long long k = __ballot(m);
              if (m) idx[pos + __popcll(k & ((1ull << lane) - 1ull))] = gbase + 3; pos += __popcll(k); }
        }
        if (t == 0) {
            int s = 0;
#pragma unroll
            for (int i = 0; i < 16; i++) s += wcnt[i];
            cnt[c] = s;
        }
    }
}

// ------- kernel 2: main — R9 structure + batch-issued gather (T14 split) -----
__launch_bounds__(256, 2)
__global__ void k_main(const float* __restrict__ x,
                       const short* __restrict__ cni,
                       const int* __restrict__ cnt,
                       const int* __restrict__ idx,
                       float* __restrict__ partials) {
    __shared__ __align__(16) short c_lds[KC * DD];   // 32 KiB bf16, XOR-swizzled
    __shared__ __align__(16) short x_lds[32 * DD];   // 32 KiB bf16, XOR-swizzled
    __shared__ float S_lds[32][33];
    __shared__ float xinv[32];
    __shared__ float red[256];

    int c = blockIdx.x >> 3;
    int p = blockIdx.x & 7;
    int n = cnt[c];
    int nch = (n + 31) >> 5;
    int t = threadIdx.x, w = t >> 6, lane = t & 63;
    float loss_acc = 0.f;

    if (p < nch) {
        const short* cbase = cni + (size_t)c * KC * DD;
#pragma unroll
        for (int it = 0; it < 8; it++) {
            int q = t + 256 * it;                 // 16B chunk 0..2047, linear LDS
            int drow = q >> 6, cc = q & 63;
            gload_lds16(cbase + drow * DD + (cc ^ (drow & 7)) * 8, &c_lds[q * 8]);
        }

        int base = c * BUCKET;
        int mrow = ((w & 1) << 4) + (lane & 15);
        int nrow = ((w >> 1) << 4) + (lane & 15);
        int row8 = t >> 3, l8 = t & 7;            // 8 threads per sample row

        for (int ch = p; ch < nch; ch += 8) {
            int off = ch << 5;
            int rem = n - off;                    // > 0

            // ---- gather raw f32 x row: ISSUE ALL 16 LOADS FIRST (T14) ----
            {
                int r = (row8 < rem) ? row8 : (rem - 1);
                int g = idx[base + off + r];
                const float4* src = (const float4*)(x + (size_t)g * DD);
                float4 va[8], vb[8];
#pragma unroll
                for (int jj = 0; jj < 8; jj++) {   // 16 independent 16B loads,
                    va[jj] = src[2 * l8 + 16 * jj];        // no intervening uses
                    vb[jj] = src[2 * l8 + 16 * jj + 1];    // -> one latency round
                }
                float nrm = 0.f;
#pragma unroll
                for (int jj = 0; jj < 8; jj++) {   // use phase: norm + cvt + LDS
                    int cc = l8 + 8 * jj;          // 16B bf16 chunk 0..63
                    float4 a = va[jj], b = vb[jj];
                    nrm += a.x * a.x + a.y * a.y + a.z * a.z + a.w * a.w
                         + b.x * b.x + b.y * b.y + b.z * b.z + b.w * b.w;
                    *(short8*)&x_lds[row8 * DD + ((cc ^ (row8 & 7)) << 3)] = pack8(a, b);
                }
#pragma unroll
                for (int m = 1; m < 8; m <<= 1) nrm += __shfl_xor(nrm, m, 64);
                if (l8 == 0) xinv[row8] = rsqrtf(nrm + 1e-12f);
            }
            __syncthreads();

            // ---- MFMA: S[32 samples][32 k] in 4 wave-quadrants ----
            fx4 acc = {0.f, 0.f, 0.f, 0.f};
#pragma unroll
            for (int ks = 0; ks < 16; ks++) {
                int c16a = ks * 4 + (lane >> 4);
                short8 av = *(const short8*)&x_lds[mrow * DD + ((c16a ^ (mrow & 7)) << 3)];
                short8 bv = *(const short8*)&c_lds[nrow * DD + ((c16a ^ (nrow & 7)) << 3)];
                acc = __builtin_amdgcn_mfma_f32_16x16x32_bf16(av, bv, acc, 0, 0, 0);
            }
#pragma unroll
            for (int j = 0; j < 4; j++) {
                int r = ((w & 1) << 4) + ((lane >> 4) << 2) + j;   // C/D row
                int col = ((w >> 1) << 4) + (lane & 15);           // C/D col
                S_lds[r][col] = acc[j];
            }
            __syncthreads();

            // ---- softmax over K=32 + per-sample loss; 8 threads per row ----
            {
                float xv = xinv[row8];
                int q4 = l8 << 2;
                float s0 = S_lds[row8][q4 + 0] * xv;
                float s1 = S_lds[row8][q4 + 1] * xv;
                float s2 = S_lds[row8][q4 + 2] * xv;
                float s3 = S_lds[row8][q4 + 3] * xv;
                float mx = fmaxf(fmaxf(s0, s1), fmaxf(s2, s3));
#pragma unroll
                for (int m = 1; m < 8; m <<= 1) mx = fmaxf(mx, __shfl_xor(mx, m, 64));
                float e0 = expf(s0 - mx), e1 = expf(s1 - mx);
                float e2 = expf(s2 - mx), e3 = expf(s3 - mx);
                float Z = e0 + e1 + e2 + e3;
                float num = e0 * (1.f - s0) + e1 * (1.f - s1)
                          + e2 * (1.f - s2) + e3 * (1.f - s3);
#pragma unroll
                for (int m = 1; m < 8; m <<= 1) {
                    Z += __shfl_xor(Z, m, 64);
                    num += __shfl_xor(num, m, 64);
                }
                if (l8 == 0 && row8 < rem) loss_acc += num / Z;
            }
            __syncthreads();   // protect x_lds/S_lds before next chunk
        }
    }

    // ---- per-block fixed-order partial reduction ----
    red[t] = loss_acc;
    __syncthreads();
    for (int h = 128; h > 0; h >>= 1) {
        if (t < h) red[t] += red[t + h];
        __syncthreads();
    }
    if (t == 0) partials[blockIdx.x] = red[0];
}

// ------- kernel 3: deterministic final mean over 720 block partials ----------
__global__ void k_final(const float* __restrict__ partials, float* __restrict__ out) {
    __shared__ float red[256];
    int t = threadIdx.x;
    float s = 0.f;
    for (int i = t; i < NCLS * 8; i += 256) s += partials[i];
    red[t] = s;
    __syncthreads();
    for (int h = 128; h > 0; h >>= 1) {
        if (t < h) red[t] += red[t + h];
        __syncthreads();
    }
    if (t == 0) out[0] = red[0] * (1.0f / (float)BB);
}

extern "C" void kernel_launch(void* const* d_in, const int* in_sizes, int n_in,
                              void* d_out, int out_size, void* d_ws, size_t ws_size,
                              hipStream_t stream) {
    const float* x       = (const float*)d_in[0];
    const int*   labels  = (const int*)d_in[1];
    const float* centers = (const float*)d_in[2];
    float* out = (float*)d_out;

    char* ws = (char*)d_ws;
    short* cni      = (short*)(ws + 0);             // 2880*512 bf16 = 2,949,120 B
    int*   idx      = (int*)(ws + 3145728);         // 90*512 ints   =   184,320 B
    int*   cnt      = (int*)(ws + 3407872);         // 90 ints
    float* partials = (float*)(ws + 3473408);       // 720 floats

    k_prep<<<PRB + NCLS, 1024, 0, stream>>>(centers, labels, cni, idx, cnt);
    k_main<<<NCLS * 8, 256, 0, stream>>>(x, cni, cnt, idx, partials);
    k_final<<<1, 256, 0, stream>>>(partials, out);
}